// Round 6
// baseline (321.246 us; speedup 1.0000x reference)
//
#include <hip/hip_runtime.h>
#include <hip/hip_bf16.h>
#include <stdint.h>

typedef unsigned short u16;
typedef __bf16 bf16x8 __attribute__((ext_vector_type(8)));
typedef float f32x4 __attribute__((ext_vector_type(4)));
typedef unsigned short u16x8 __attribute__((ext_vector_type(8)));

#define QEPS 1e-8f

__device__ __forceinline__ u16 f32_to_bf16_rne(float f) {
    uint32_t u = __float_as_uint(f);
    u += 0x7fffu + ((u >> 16) & 1u);
    return (u16)(u >> 16);
}

// ---------------- x: f32 -> bf16, [M][K] row-major ----------------
__global__ void cvt_x_bf16(const float* __restrict__ x, u16* __restrict__ xb, int n8) {
    int idx = blockIdx.x * blockDim.x + threadIdx.x;
    if (idx >= n8) return;
    const float4* p = (const float4*)(x + (size_t)idx * 8);
    float4 a = p[0], b = p[1];
    u16x8 r;
    r[0] = f32_to_bf16_rne(a.x); r[1] = f32_to_bf16_rne(a.y);
    r[2] = f32_to_bf16_rne(a.z); r[3] = f32_to_bf16_rne(a.w);
    r[4] = f32_to_bf16_rne(b.x); r[5] = f32_to_bf16_rne(b.y);
    r[6] = f32_to_bf16_rne(b.z); r[7] = f32_to_bf16_rne(b.w);
    *(u16x8*)(xb + (size_t)idx * 8) = r;
}

// ------- weight dequant: w_dq[n][k] = round(w/s)*s, bf16, [N][K] -------
__global__ void dequant_w_bf16(const float* __restrict__ w, const float* __restrict__ ss,
                               u16* __restrict__ wb, int N, int K) {
    int idx = blockIdx.x * blockDim.x + threadIdx.x;
    int pr = K >> 3;
    if (idx >= N * pr) return;
    int n = idx / pr;
    int k8 = (idx - n * pr) << 3;
    float s = ss[(size_t)(k8 >> 7) * N + n] + QEPS;
    const float4* p = (const float4*)(w + (size_t)n * K + k8);
    float4 a = p[0], b = p[1];
    float v[8] = {a.x, a.y, a.z, a.w, b.x, b.y, b.z, b.w};
    u16x8 r;
#pragma unroll
    for (int i = 0; i < 8; ++i) {
        float q = rintf(v[i] / s);
        r[i] = f32_to_bf16_rne(q * s);
    }
    *(u16x8*)(wb + (size_t)n * K + k8) = r;
}

// ======================= 256x128 bf16 GEMM, 2 blocks/CU =======================
// 8 waves (4 rows x 2 cols), per-wave 64x64 (acc=64 regs -> 4 waves/SIMD).
// Ring-3 of BK=32 slabs (72 KiB LDS -> 2 blocks/CU), lookahead-2, vmcnt(3).
// Cross-BLOCK overlap fills the MFMA pipe during each block's stage/barrier.
#define BM 256
#define BN 128
#define SLOTB 24576     // A 16 KiB (256 rows x 64 B) + B 8 KiB (128 rows x 64 B)
#define ABYT 16384
#define LDSB 73728      // 3 slots

#define ASYNC16(g, l)                                                                      \
    __builtin_amdgcn_global_load_lds((const __attribute__((address_space(1))) void*)(g),   \
                                     (__attribute__((address_space(3))) void*)(l), 16, 0, 0)
#define VMCNT(n) asm volatile("s_waitcnt vmcnt(" #n ")" ::: "memory")
#define BAR()    __builtin_amdgcn_s_barrier()
#define MFMA(a, b, c) __builtin_amdgcn_mfma_f32_16x16x32_bf16((a), (b), (c), 0, 0, 0)

__global__ __launch_bounds__(512, 4) void gemm_bf16_bt_v6(
        const u16* __restrict__ A,    // [M][K] bf16
        const u16* __restrict__ B,    // [N][K] bf16
        const float* __restrict__ bias,
        float* __restrict__ C,        // [M][N] f32
        int M, int N, int K) {
    extern __shared__ char lds[];
    const int tid  = threadIdx.x;
    const int wave = tid >> 6;
    const int lane = tid & 63;

    // XCD-aware bijective swizzle (grid 1024, %8==0)
    const int nwg = gridDim.x;
    const int cpx = nwg >> 3;
    const int bid = blockIdx.x;
    const int swz = (bid & 7) * cpx + (bid >> 3);
    const int nbn = N / BN;                  // 32
    const int bm  = swz / nbn;
    const int bn  = swz - bm * nbn;

    const int wr = wave >> 1;                // 0..3 -> 64-row band
    const int wc = wave & 1;                 // 0..1 -> 64-col band

    // staging sources (k pre-swizzled: kb ^= ((row>>1)&3)<<4, involution in 64-B row)
    const int srow  = tid >> 2;                                        // 0..127
    const int kbsrc = ((tid & 3) << 4) ^ (((tid >> 3) & 3) << 4);
    const char* gA0 = (const char*)A + ((size_t)(bm * BM + srow) * K) * 2 + kbsrc;
    const char* gA1 = (const char*)A + ((size_t)(bm * BM + 128 + srow) * K) * 2 + kbsrc;
    const char* gB0 = (const char*)B + ((size_t)(bn * BN + srow) * K) * 2 + kbsrc;

    // ring slot index without %3 in the hot loop: caller passes t%3 via rotation
    auto STAGE = [&](int t, int slot) {
        const size_t ko = (size_t)t << 6;               // t * 32k * 2B
        char* d = lds + slot * SLOTB + (wave << 10);
        ASYNC16(gA0 + ko, d);
        ASYNC16(gA1 + ko, d + 8192);
        ASYNC16(gB0 + ko, d + ABYT);
    };

    // fragment read bases (same XOR on read address; row bases are multiples of 64)
    const int kx = ((lane >> 4) ^ ((lane >> 1) & 3)) << 4;
    const char* pa = lds + (size_t)(wr * 64 + (lane & 15)) * 64 + kx;
    const char* pb = lds + ABYT + (size_t)(wc * 64 + (lane & 15)) * 64 + kx;

    f32x4 acc[4][4] = {};

#define SLAB(slot, DO_STAGE, t3, slot3, VMSTMT)                               \
    {                                                                         \
        const int bo = (slot) * SLOTB;                                        \
        bf16x8 b0 = *(const bf16x8*)(pb + bo);                                \
        bf16x8 b1 = *(const bf16x8*)(pb + bo + 1024);                         \
        bf16x8 a0 = *(const bf16x8*)(pa + bo);                                \
        bf16x8 a1 = *(const bf16x8*)(pa + bo + 1024);                         \
        bf16x8 b2 = *(const bf16x8*)(pb + bo + 2048);                         \
        bf16x8 b3 = *(const bf16x8*)(pb + bo + 3072);                         \
        if (DO_STAGE) STAGE(t3, slot3);                                       \
        __builtin_amdgcn_s_setprio(1);                                        \
        acc[0][0] = MFMA(a0, b0, acc[0][0]);                                  \
        acc[0][1] = MFMA(a0, b1, acc[0][1]);                                  \
        acc[0][2] = MFMA(a0, b2, acc[0][2]);                                  \
        acc[0][3] = MFMA(a0, b3, acc[0][3]);                                  \
        bf16x8 a2 = *(const bf16x8*)(pa + bo + 2048);                         \
        acc[1][0] = MFMA(a1, b0, acc[1][0]);                                  \
        acc[1][1] = MFMA(a1, b1, acc[1][1]);                                  \
        acc[1][2] = MFMA(a1, b2, acc[1][2]);                                  \
        acc[1][3] = MFMA(a1, b3, acc[1][3]);                                  \
        bf16x8 a3 = *(const bf16x8*)(pa + bo + 3072);                         \
        acc[2][0] = MFMA(a2, b0, acc[2][0]);                                  \
        acc[2][1] = MFMA(a2, b1, acc[2][1]);                                  \
        acc[2][2] = MFMA(a2, b2, acc[2][2]);                                  \
        acc[2][3] = MFMA(a2, b3, acc[2][3]);                                  \
        acc[3][0] = MFMA(a3, b0, acc[3][0]);                                  \
        acc[3][1] = MFMA(a3, b1, acc[3][1]);                                  \
        acc[3][2] = MFMA(a3, b2, acc[3][2]);                                  \
        acc[3][3] = MFMA(a3, b3, acc[3][3]);                                  \
        __builtin_amdgcn_s_setprio(0);                                        \
        VMSTMT;                                                               \
        BAR();                                                                \
    }

    const int NT = K >> 5;                   // 128 slabs of 32 k

    // prologue: slabs 0,1 in flight (6 loads); confirm slab 0
    STAGE(0, 0); STAGE(1, 1);
    VMCNT(3);
    BAR();

    // steady state: at top of slab t stage t+2; at end vmcnt(3) confirms t+1
    int s0 = 0, s1 = 1, s2 = 2;              // slot of t, t+1, t+2
    for (int t = 0; t < NT - 2; ++t) {
        SLAB(s0, true, t + 2, s2, VMCNT(3));
        int tmp = s0; s0 = s1; s1 = s2; s2 = tmp;
    }
    SLAB(s0, false, 0, 0, VMCNT(0));
    { int tmp = s0; s0 = s1; s1 = s2; s2 = tmp; }
    SLAB(s0, false, 0, 0, (void)0);

    // ---- epilogue: C/D layout row=(lane>>4)*4+i, col=lane&15 ----
    const int r0 = bm * BM + wr * 64 + ((lane >> 4) << 2);
    const int c0 = bn * BN + wc * 64 + (lane & 15);
    float bv[4];
#pragma unroll
    for (int n = 0; n < 4; ++n) bv[n] = bias[c0 + n * 16];
#pragma unroll
    for (int m = 0; m < 4; ++m)
#pragma unroll
        for (int n = 0; n < 4; ++n)
#pragma unroll
            for (int i = 0; i < 4; ++i)
                C[(size_t)(r0 + m * 16 + i) * N + (c0 + n * 16)] = acc[m][n][i] + bv[n];
}

extern "C" void kernel_launch(void* const* d_in, const int* in_sizes, int n_in,
                              void* d_out, int out_size, void* d_ws, size_t ws_size,
                              hipStream_t stream) {
    const float* x    = (const float*)d_in[0];   // [B,S,K] f32
    const float* w    = (const float*)d_in[1];   // [N,K]   f32
    const float* bias = (const float*)d_in[2];   // [N]     f32
    const float* ss   = (const float*)d_in[3];   // [K/128, N] f32
    float* out        = (float*)d_out;           // [B,S,N] f32

    const int N = in_sizes[2];            // 4096
    const int K = in_sizes[1] / N;        // 4096
    const int M = in_sizes[0] / K;        // 8192

    u16* xb = (u16*)d_ws;                        // [M][K] bf16
    u16* wb = xb + (size_t)M * K;                // [N][K] bf16

    int n8x = (M * K) >> 3;
    cvt_x_bf16<<<(n8x + 255) / 256, 256, 0, stream>>>(x, xb, n8x);

    int n8w = (N * K) >> 3;
    dequant_w_bf16<<<(n8w + 255) / 256, 256, 0, stream>>>(w, ss, wb, N, K);

    (void)hipFuncSetAttribute((const void*)gemm_bf16_bt_v6,
                              hipFuncAttributeMaxDynamicSharedMemorySize, LDSB);
    dim3 grid((M / BM) * (N / BN));              // 32*32 = 1024, %8 == 0
    gemm_bf16_bt_v6<<<grid, 512, LDSB, stream>>>(xb, wb, bias, out, M, N, K);
}